// Round 6
// baseline (490.173 us; speedup 1.0000x reference)
//
#include <hip/hip_runtime.h>

// ---------------------------------------------------------------------------
// RGCN (basis decomposition), 2 layers. N=50000, E=1e6, H=128, O=64, R=16.
// Round 15: r10/r11/r14 pipeline-scheduling changes all null -> VMEM latency
// is NOT the wall. Model: 3 waves/SIMD (LDS-capped) x ~900cy serial chain
// per wave-phase (xs->GEMM1, then ys pack->ds_write->lgkm->ds_read->agg
// round-trip) == 2000cy/block-phase. Fix chain + occupancy:
//  - ELIMINATE ys entirely. Layout algebra: dacc (col=l16, edge=mt*16+
//    quad*4+reg) vs agg B-frag (col=l16, k=quad*8+j) share l16; with k-slot
//    permutation eps(k)=m*16+q*4+r (k=[q(2b),m(1b),r(2b)]), lane-local pack
//    bfv = {pk(d0r0,d0r1),pk(d0r2,d0r3),pk(d1r0,d1r1),pk(d1r2,d1r3)} IS the
//    B-fragment (v_cvt_pk_bf16_f32, no cross-lane, no LDS). pmat columns
//    move to slot eps^-1(e) = ((e>>2)&3)*8 + ((e>>4)&1)*4 + (e&3) - a
//    per-thread constant for the handler. agg math unchanged otherwise.
//  - ys LDS (10.2K) freed -> 31.2KB total -> 4 blocks/CU (16 waves, +33%
//    TLP), __launch_bounds__(256,4) (VGPR<=128).
// Kept from r14: ping/pong depth-2 pipeline, xs staging, pmat handler
// scatter+clear (column now eps^-1), barrier_nodrain, setprio, epilogue.
// Stale xs rows stay finite (zero-init + finite writes) so garbage B slots
// are killed by pmat==0 without NaN risk.
// ---------------------------------------------------------------------------

typedef short bf16x8 __attribute__((ext_vector_type(8)));
typedef float f32x4 __attribute__((ext_vector_type(4)));

#define RELS 16
#define HDIM 128
#define DSTBLK 66
#define MT_P 5    // ceil(66/16): pmat has 80 rows
#define CHUNK 32
#define MAXBINS 12288
#define MAXCH 96  // chunks/block: mean ~49; needs edges>2592 (35 sigma) to overflow

__device__ inline unsigned short f2bf(float f) {
  unsigned int u = __float_as_uint(f);
  unsigned int r = u + 0x7FFFu + ((u >> 16) & 1u);
  return (unsigned short)(r >> 16);
}

// packed bf16 pair via HW cvt (RNE); no builtin on gfx950 -> inline asm
__device__ inline unsigned cvtpk(float lo, float hi) {
  unsigned r;
  asm("v_cvt_pk_bf16_f32 %0, %1, %2" : "=v"(r) : "v"(lo), "v"(hi));
  return r;
}

// Workgroup barrier WITHOUT the vmcnt(0) drain __syncthreads() emits.
// Correct here because inter-wave communication is exclusively through LDS:
// lgkmcnt(0) makes all DS writes visible; in-flight global loads only feed
// this wave's registers (compiler inserts counted vmcnt at first use).
__device__ inline void barrier_nodrain() {
  __builtin_amdgcn_sched_barrier(0);
  asm volatile("s_waitcnt lgkmcnt(0)" ::: "memory");
  __builtin_amdgcn_s_barrier();
  __builtin_amdgcn_sched_barrier(0);
}

__global__ void cvt_bf16(const float* __restrict__ in, unsigned short* __restrict__ out, int n8) {
  int i = blockIdx.x * blockDim.x + threadIdx.x;
  if (i >= n8) return;
  float4 a = ((const float4*)in)[i * 2];
  float4 b = ((const float4*)in)[i * 2 + 1];
  uint4 o;
  o.x = (unsigned)f2bf(a.x) | ((unsigned)f2bf(a.y) << 16);
  o.y = (unsigned)f2bf(a.z) | ((unsigned)f2bf(a.w) << 16);
  o.z = (unsigned)f2bf(b.x) | ((unsigned)f2bf(b.y) << 16);
  o.w = (unsigned)f2bf(b.z) | ((unsigned)f2bf(b.w) << 16);
  ((uint4*)out)[i] = o;
}

// Wt[r][o][k] (bf16, transposed) = sum_b comp[r,b] * V[b,k,o]
__global__ void compute_w(const float* __restrict__ comp, const float* __restrict__ V,
                          unsigned short* __restrict__ Wt, int IO) {
  int idx = blockIdx.x * blockDim.x + threadIdx.x;
  if (idx >= RELS * IO * HDIM) return;
  int k = idx & (HDIM - 1);
  int o = (idx >> 7) % IO;
  int r = idx / (IO * HDIM);
  float s = 0.f;
#pragma unroll
  for (int b = 0; b < RELS; b++)
    s = fmaf(comp[r * RELS + b], V[(size_t)b * HDIM * IO + (size_t)k * IO + o], s);
  Wt[idx] = f2bf(s);
}

__global__ void hist_bins(const int* __restrict__ dst, const int* __restrict__ etype,
                          int n, int nbins, int* __restrict__ counts) {
  __shared__ int lh[MAXBINS];
  for (int j = threadIdx.x; j < nbins; j += blockDim.x) lh[j] = 0;
  __syncthreads();
  for (int i = blockIdx.x * blockDim.x + threadIdx.x; i < n; i += gridDim.x * blockDim.x)
    atomicAdd(&lh[(dst[i] / DSTBLK) * RELS + etype[i]], 1);
  __syncthreads();
  for (int j = threadIdx.x; j < nbins; j += blockDim.x) {
    int c = lh[j];
    if (c) atomicAdd(&counts[j], c);
  }
}

// exclusive scan of counts padded to multiples of 16 (parallel prefix)
__global__ void scan_offsets(const int* __restrict__ counts, int* __restrict__ offsets, int nbins) {
  __shared__ int csum[256];
  const int t = threadIdx.x;
  const int CH = (nbins + 255) / 256;
  int lo = t * CH, hi = min(lo + CH, nbins);
  int s = 0;
  for (int i = lo; i < hi; i++) s += (counts[i] + 15) & ~15;
  csum[t] = s;
  __syncthreads();
#pragma unroll
  for (int d = 1; d < 256; d <<= 1) {  // Hillis-Steele inclusive scan
    int v = (t >= d) ? csum[t - d] : 0;
    __syncthreads();
    csum[t] += v;
    __syncthreads();
  }
  int run = (t == 0) ? 0 : csum[t - 1];
  for (int i = lo; i < hi; i++) {
    offsets[i] = run;
    run += (counts[i] + 15) & ~15;
  }
  if (lo < nbins && hi == nbins) offsets[nbins] = run;
}

// ebuf[p] = {src | dloc<<20, norm_f32_bits}; dloc = d % DSTBLK (7 bits).
// Pad slots unwritten; all consumers guard by real counts.
__global__ void scatter_bins(const int* __restrict__ src, const int* __restrict__ dst,
                             const int* __restrict__ etype, const float* __restrict__ norm,
                             int n, const int* __restrict__ offsets, int* __restrict__ cursor,
                             uint2* __restrict__ ebuf) {
  for (int i = blockIdx.x * blockDim.x + threadIdx.x; i < n; i += gridDim.x * blockDim.x) {
    int d = dst[i];
    int blk = d / DSTBLK;
    int b = blk * RELS + etype[i];
    int p = offsets[b] + atomicAdd(&cursor[b], 1);
    ebuf[p] = make_uint2((unsigned)src[i] | ((unsigned)(d - blk * DSTBLK) << 20),
                         __float_as_uint(norm[i]));
  }
}

// One block owns DSTBLK nodes; walks a precomputed chunk-descriptor list.
// Depth-2 pipeline, 2x unrolled with ping/pong register sets. Phase ci
// (parity cb): (1) entries(ci+3)+hentry(ci+2) -> OUT set, (2) GEMM1 on
// xs[cb] -> dacc regs, (3) gathers(ci+2) from IN entries, (4) lane-local
// cvt_pk pack (B-frag) + agg pacc += pmat[cb] @ B, (5) write xs[cb^1]/
// pmat[cb^1] (eps^-1 column) for ci+1 from IN set, (6) barrier_nodrain.
// Wave w owns out columns [w*OUT/4, +OUT/4).
template <int OUT, bool BF16_RELU_OUT>
__launch_bounds__(256, 4)
__global__ void rgcn_layer(const unsigned short* __restrict__ Xb,  // [N][128] bf16
                           const unsigned short* __restrict__ Wt,  // [R][OUT][128] bf16
                           const uint2* __restrict__ ebuf,
                           const int* __restrict__ offsets, const int* __restrict__ counts,
                           const float* __restrict__ bias, void* __restrict__ Hout,
                           int nNodes) {
  constexpr int NT = OUT / 64;  // 2 (OUT=128) or 1 (OUT=64)
  __shared__ __align__(16) unsigned short xs[2][CHUNK][136];  // gathered src rows
  __shared__ __align__(16) unsigned short pmat[2][80][40];    // P[dloc][slot] = bf16(norm)
  __shared__ __align__(8) int2 descS[MAXCH];                  // {base, nRows|rel<<8}
  __shared__ int sBase[16], sCnt[16], sStart[17];

  const int t = threadIdx.x;
  const int w = t >> 6;
  const int lane = t & 63;
  const int quad = lane >> 4;
  const int l16 = lane & 15;
  const int r0 = t >> 4;     // gather row (this thread covers rows r0, r0+16)
  const int k8 = t & 15;     // gather 8-elem column piece
  const bool isHandler = (t & 7) == 0;
  const int myCol = t >> 3;  // handler-owned edge index (0..31, fixed)
  // pmat column slot for edge myCol: eps^-1(e) = q*8 + m*4 + r
  const int hslot = ((myCol >> 2) & 3) * 8 + ((myCol >> 4) & 1) * 4 + (myCol & 3);
  const int nodeBase = blockIdx.x * DSTBLK;
  const int binBase = blockIdx.x * RELS;
  const int colBase = w * (OUT / 4);

  // one-time zero (stale LDS may hold NaN bit patterns; 0 * NaN = NaN)
  for (int i = t; i < 2 * CHUNK * 136 / 8; i += 256) ((uint4*)xs)[i] = make_uint4(0, 0, 0, 0);
  for (int i = t; i < 2 * 80 * 40 / 8; i += 256) ((uint4*)pmat)[i] = make_uint4(0, 0, 0, 0);

  // build chunk descriptor list (bins in relation order -> few W reloads)
  if (t < 16) {
    sBase[t] = offsets[binBase + t];
    sCnt[t] = counts[binBase + t];
  }
  __syncthreads();  // covers zero-init + sBase/sCnt (nothing in flight yet)
  if (t == 0) {
    int run = 0;
#pragma unroll
    for (int b = 0; b < 16; b++) {
      sStart[b] = run;
      run += (sCnt[b] + CHUNK - 1) / CHUNK;
    }
    sStart[16] = min(run, MAXCH);
  }
  __syncthreads();
  if (t < 16) {
    int st = sStart[t], ba = sBase[t], c = sCnt[t];
    for (int j = 0; j * CHUNK < c; j++)
      if (st + j < MAXCH)
        descS[st + j] = make_int2(ba + j * CHUNK, min(CHUNK, c - j * CHUNK) | (t << 8));
  }
  __syncthreads();
  const int nCh = sStart[16];

  f32x4 pacc[MT_P][NT] = {};  // persistent dst accumulator

  // ping/pong pipeline register sets (live across one barrier each; no movs)
  struct Pipe {
    uint2 E0, E1;  // ebuf entries (rows r0, 16+r0) for the chunk gathered next phase
    uint4 G0, G1;  // gathered xs rows, written to LDS next phase
    uint2 H;       // handler ebuf entry, written to pmat next phase
  };
  Pipe P, Q;
  int pd0 = -1, pd1 = -1;  // handler prev-entry tracker per pmat buffer
  int n1 = 0, n2 = 0;      // rows(ci+1), rows(ci+2)

  // prologue (acts as phase -1): stage chunk 0; prime Q = {entries(2),
  // gathers(1), hentry(1)}; full latency exposed once per block.
  if (nCh > 0) {
    int2 d0 = descS[0];
    int2 d1 = (nCh > 1) ? descS[1] : make_int2(0, 0);
    int2 d2 = (nCh > 2) ? descS[2] : make_int2(0, 0);
    const int rows0 = d0.y & 0xFF;
    n1 = d1.y & 0xFF;
    n2 = d2.y & 0xFF;
    uint2 a0, a1, am, e10, e11;
    if (r0 < rows0) a0 = ebuf[d0.x + r0];
    if (16 + r0 < rows0) a1 = ebuf[d0.x + 16 + r0];
    if (isHandler && myCol < rows0) am = ebuf[d0.x + myCol];
    if (r0 < n1) e10 = ebuf[d1.x + r0];
    if (16 + r0 < n1) e11 = ebuf[d1.x + 16 + r0];
    if (isHandler && myCol < n1) Q.H = ebuf[d1.x + myCol];
    if (r0 < n2) Q.E0 = ebuf[d2.x + r0];
    if (16 + r0 < n2) Q.E1 = ebuf[d2.x + 16 + r0];
    // stage chunk 0 into xs[0]/pmat[0]
    if (r0 < rows0)
      *(uint4*)&xs[0][r0][k8 * 8] =
          *(const uint4*)(Xb + (size_t)(a0.x & 0xFFFFFu) * HDIM + k8 * 8);
    if (16 + r0 < rows0)
      *(uint4*)&xs[0][16 + r0][k8 * 8] =
          *(const uint4*)(Xb + (size_t)(a1.x & 0xFFFFFu) * HDIM + k8 * 8);
    if (isHandler && myCol < rows0) {
      int dl = (int)(am.x >> 20) & 127;
      pmat[0][dl][hslot] = f2bf(__uint_as_float(am.y));
      pd0 = dl;
    }
    // issue gathers for chunk 1 (e1* landed or nearly so by now)
    if (r0 < n1) Q.G0 = *(const uint4*)(Xb + (size_t)(e10.x & 0xFFFFFu) * HDIM + k8 * 8);
    if (16 + r0 < n1) Q.G1 = *(const uint4*)(Xb + (size_t)(e11.x & 0xFFFFFu) * HDIM + k8 * 8);
  }
  barrier_nodrain();  // Q prefetches stay in flight

  int curRel = -1;
  bf16x8 wf[4][NT];

  // phase body; cbv is a literal 0/1 at each call site -> static LDS indices
  auto phase = [&](int ci, int cbv, Pipe& in, Pipe& out, int n1v, int n2v,
                   int& pdW) -> int {
    int2 dc = descS[ci];
    const int nRows = dc.y & 0xFF;
    const int rel = dc.y >> 8;

    if (rel != curRel) {  // W fragments for this relation (register-resident)
      curRel = rel;
      const unsigned short* Wr = Wt + (size_t)rel * OUT * HDIM;
#pragma unroll
      for (int ks = 0; ks < 4; ks++)
#pragma unroll
        for (int nt = 0; nt < NT; nt++)
          wf[ks][nt] = *(const bf16x8*)(Wr + (size_t)(colBase + nt * 16 + l16) * HDIM + ks * 32 + quad * 8);
    }

    // ---- (1) births: entries(ci+3) -> out.E*, hentry(ci+2) -> out.H ----
    int2 d3 = (ci + 3 < nCh) ? descS[ci + 3] : make_int2(0, 0);
    const int n3 = d3.y & 0xFF;
    if (r0 < n3) out.E0 = ebuf[d3.x + r0];
    if (16 + r0 < n3) out.E1 = ebuf[d3.x + 16 + r0];
    if (isHandler && myCol < n2v) out.H = ebuf[descS[ci + 2].x + myCol];

    // ---- (2) GEMM1: dacc = xs[cbv] @ W_r (f32, stays in registers) ----
    f32x4 dacc[2][NT] = {};
#pragma unroll
    for (int mt = 0; mt < 2; mt++) {
      if (mt * 16 < nRows) {  // wave-uniform
        __builtin_amdgcn_s_setprio(1);
#pragma unroll
        for (int ks = 0; ks < 4; ks++) {
          bf16x8 a = *(const bf16x8*)&xs[cbv][mt * 16 + l16][ks * 32 + quad * 8];
#pragma unroll
          for (int nt = 0; nt < NT; nt++)
            dacc[mt][nt] = __builtin_amdgcn_mfma_f32_16x16x32_bf16(a, wf[ks][nt], dacc[mt][nt], 0, 0, 0);
        }
        __builtin_amdgcn_s_setprio(0);
      }
    }

    // ---- (3) issue gathers(ci+2) from IN entries (landed: 1 phase cover) ----
    if (r0 < n2v) out.G0 = *(const uint4*)(Xb + (size_t)(in.E0.x & 0xFFFFFu) * HDIM + k8 * 8);
    if (16 + r0 < n2v) out.G1 = *(const uint4*)(Xb + (size_t)(in.E1.x & 0xFFFFFu) * HDIM + k8 * 8);

    // ---- (4) lane-local pack -> B-frag; agg pacc += pmat[cbv] @ B ----
    // dacc (col=l16, edge=mt*16+quad*4+reg) IS B-frag (col=l16, k=quad*8+j)
    // under slot permutation eps; pmat columns are written eps^-1-permuted.
    {
      bf16x8 bfv[NT];
#pragma unroll
      for (int nt = 0; nt < NT; nt++) {
        uint4 bw;
        bw.x = cvtpk(dacc[0][nt][0], dacc[0][nt][1]);
        bw.y = cvtpk(dacc[0][nt][2], dacc[0][nt][3]);
        bw.z = cvtpk(dacc[1][nt][0], dacc[1][nt][1]);
        bw.w = cvtpk(dacc[1][nt][2], dacc[1][nt][3]);
        bfv[nt] = *(bf16x8*)&bw;
      }
      __builtin_amdgcn_s_setprio(1);
#pragma unroll
      for (int mt = 0; mt < MT_P; mt++) {
        bf16x8 a = *(const bf16x8*)&pmat[cbv][mt * 16 + l16][quad * 8];
#pragma unroll
        for (int nt = 0; nt < NT; nt++)
          pacc[mt][nt] = __builtin_amdgcn_mfma_f32_16x16x32_bf16(a, bfv[nt], pacc[mt][nt], 0, 0, 0);
      }
      __builtin_amdgcn_s_setprio(0);
    }

    // ---- (5) write chunk ci+1 from IN gathers/hentry (1 phase of cover;
    //          counted vmcnt here, newer out.* loads stay in flight) ----
    if (r0 < n1v) *(uint4*)&xs[cbv ^ 1][r0][k8 * 8] = in.G0;
    if (16 + r0 < n1v) *(uint4*)&xs[cbv ^ 1][16 + r0][k8 * 8] = in.G1;
    if (isHandler) {
      if (pdW >= 0) pmat[cbv ^ 1][pdW][hslot] = 0;  // clear own old entry
      if (myCol < n1v) {
        int dl = (int)(in.H.x >> 20) & 127;
        pmat[cbv ^ 1][dl][hslot] = f2bf(__uint_as_float(in.H.y));
        pdW = dl;
      } else {
        pdW = -1;
      }
    }

    if (ci + 1 < nCh) barrier_nodrain();  // block-uniform condition
    return n3;
  };

  // 2x-unrolled driver: even phases read Q write P; odd phases reverse.
  int ci = 0;
  while (ci < nCh) {
    int n3 = phase(ci, 0, Q, P, n1, n2, pd1);
    n1 = n2; n2 = n3; ci++;
    if (ci >= nCh) break;
    n3 = phase(ci, 1, P, Q, n1, n2, pd0);
    n1 = n2; n2 = n3; ci++;
  }

  // epilogue: each (node, col) owned by exactly one lane -> plain stores
#pragma unroll
  for (int mt = 0; mt < MT_P; mt++) {
#pragma unroll
    for (int reg = 0; reg < 4; reg++) {
      int ld = mt * 16 + quad * 4 + reg;
      int node = nodeBase + ld;
      if (ld < DSTBLK && node < nNodes) {
#pragma unroll
        for (int nt = 0; nt < NT; nt++) {
          int col = colBase + nt * 16 + l16;
          float v = pacc[mt][nt][reg] + bias[col];
          if constexpr (BF16_RELU_OUT)
            ((unsigned short*)Hout)[(size_t)node * OUT + col] = f2bf(fmaxf(v, 0.f));
          else
            ((float*)Hout)[(size_t)node * OUT + col] = v;
        }
      }
    }
  }
}

extern "C" void kernel_launch(void* const* d_in, const int* in_sizes, int n_in,
                              void* d_out, int out_size, void* d_ws, size_t ws_size,
                              hipStream_t stream) {
  const int*   src   = (const int*)d_in[1];
  const int*   dst   = (const int*)d_in[2];
  const int*   etype = (const int*)d_in[3];
  const float* norm  = (const float*)d_in[4];
  const float* emb   = (const float*)d_in[5];
  const float* V1    = (const float*)d_in[6];
  const float* comp1 = (const float*)d_in[7];
  const float* bias1 = (const float*)d_in[8];
  const float* V2    = (const float*)d_in[9];
  const float* comp2 = (const float*)d_in[10];
  const float* bias2 = (const float*)d_in[11];
  float* out = (float*)d_out;

  const int N = in_sizes[0];  // 50000
  const int E = in_sizes[1];  // 1000000
  const int H = 128, O = 64;
  const int NB = (N + DSTBLK - 1) / DSTBLK;  // 758
  const int NBINS = NB * RELS;               // 12128
  const int EPAD_MAX = E + NBINS * 16;

  char* ws = (char*)d_ws;
  size_t off = 0;
  auto alloc = [&](size_t bytes) -> void* {
    void* p = ws + off;
    off += (bytes + 255) & ~(size_t)255;
    return p;
  };
  unsigned short* W1t  = (unsigned short*)alloc(sizeof(short) * RELS * H * H);
  unsigned short* W2t  = (unsigned short*)alloc(sizeof(short) * RELS * O * H);
  unsigned short* embh = (unsigned short*)alloc(sizeof(short) * (size_t)N * H);
  unsigned short* h1b  = (unsigned short*)alloc(sizeof(short) * (size_t)N * H);
  uint2* ebuf = (uint2*)alloc(sizeof(uint2) * EPAD_MAX);
  int* counts  = (int*)alloc(sizeof(int) * NBINS);
  int* cursor  = (int*)alloc(sizeof(int) * NBINS);
  int* offsets = (int*)alloc(sizeof(int) * (NBINS + 1));

  hipMemsetAsync(counts, 0, sizeof(int) * NBINS, stream);
  hipMemsetAsync(cursor, 0, sizeof(int) * NBINS, stream);

  cvt_bf16<<<((size_t)N * H / 8 + 255) / 256, 256, 0, stream>>>(emb, embh, N * H / 8);
  compute_w<<<(RELS * H * H + 255) / 256, 256, 0, stream>>>(comp1, V1, W1t, H);
  compute_w<<<(RELS * O * H + 255) / 256, 256, 0, stream>>>(comp2, V2, W2t, O);
  hist_bins<<<256, 256, 0, stream>>>(dst, etype, E, NBINS, counts);
  scan_offsets<<<1, 256, 0, stream>>>(counts, offsets, NBINS);
  scatter_bins<<<1024, 256, 0, stream>>>(src, dst, etype, norm, E, offsets, cursor, ebuf);

  rgcn_layer<128, true><<<NB, 256, 0, stream>>>(embh, W1t, ebuf, offsets, counts, bias1, (void*)h1b, N);
  rgcn_layer<64, false><<<NB, 256, 0, stream>>>(h1b, W2t, ebuf, offsets, counts, bias2, (void*)out, N);
}

// Round 7
// 425.376 us; speedup vs baseline: 1.1523x; 1.1523x over previous
//
#include <hip/hip_runtime.h>

// ---------------------------------------------------------------------------
// RGCN (basis decomposition), 2 layers. N=50000, E=1e6, H=128, O=64, R=16.
// Round 16: r15 (ys-elimination via eps-permutation + cvt_pk) PASSED
// correctness but regressed 125->197us/layer from SCRATCH: WRITE_SIZE
// 12.5MB->240MB, VGPR 76->64 -> the Pipe structs passed by reference into
// the phase lambda were demoted to scratch (rule-#20 failure), and
// launch_bounds(256,4) on the NT=2 layer capped VGPR at 128 forcing spill.
// Fix (same algorithm, de-scratched):
//  - Phase body is a MACRO stamped twice with explicit scalar locals
//    (qE0..qH / pE0..pH) - ping/pong with zero rotation movs, no aggregates
//    the compiler can demote, no lambda.
//  - launch_bounds back to r14's (256,3) for OUT=128 / (256,4) for OUT=64.
// Kept from r15 (verified correct): ys GONE - dacc (col=l16, edge=
// mt*16+quad*4+reg) IS the agg B-frag (col=l16, k=quad*8+j) under slot
// permutation eps; lane-local pack via v_cvt_pk_bf16_f32; pmat written at
// hslot = eps^-1(edge) = ((e>>2)&3)*8 + ((e>>4)&1)*4 + (e&3).
// Kept from r14: ping/pong depth-2 pipeline, xs staging, handler
// scatter+clear, barrier_nodrain, setprio, epilogue, preprocessing.
// ---------------------------------------------------------------------------

typedef short bf16x8 __attribute__((ext_vector_type(8)));
typedef float f32x4 __attribute__((ext_vector_type(4)));

#define RELS 16
#define HDIM 128
#define DSTBLK 66
#define MT_P 5    // ceil(66/16): pmat has 80 rows
#define CHUNK 32
#define MAXBINS 12288
#define MAXCH 96  // chunks/block: mean ~49; needs edges>2592 (35 sigma) to overflow

__device__ inline unsigned short f2bf(float f) {
  unsigned int u = __float_as_uint(f);
  unsigned int r = u + 0x7FFFu + ((u >> 16) & 1u);
  return (unsigned short)(r >> 16);
}

// packed bf16 pair via HW cvt (RNE); no builtin on gfx950 -> inline asm
__device__ inline unsigned cvtpk(float lo, float hi) {
  unsigned r;
  asm("v_cvt_pk_bf16_f32 %0, %1, %2" : "=v"(r) : "v"(lo), "v"(hi));
  return r;
}

// Workgroup barrier WITHOUT the vmcnt(0) drain __syncthreads() emits.
// Correct here because inter-wave communication is exclusively through LDS:
// lgkmcnt(0) makes all DS writes visible; in-flight global loads only feed
// this wave's registers (compiler inserts counted vmcnt at first use).
__device__ inline void barrier_nodrain() {
  __builtin_amdgcn_sched_barrier(0);
  asm volatile("s_waitcnt lgkmcnt(0)" ::: "memory");
  __builtin_amdgcn_s_barrier();
  __builtin_amdgcn_sched_barrier(0);
}

__global__ void cvt_bf16(const float* __restrict__ in, unsigned short* __restrict__ out, int n8) {
  int i = blockIdx.x * blockDim.x + threadIdx.x;
  if (i >= n8) return;
  float4 a = ((const float4*)in)[i * 2];
  float4 b = ((const float4*)in)[i * 2 + 1];
  uint4 o;
  o.x = (unsigned)f2bf(a.x) | ((unsigned)f2bf(a.y) << 16);
  o.y = (unsigned)f2bf(a.z) | ((unsigned)f2bf(a.w) << 16);
  o.z = (unsigned)f2bf(b.x) | ((unsigned)f2bf(b.y) << 16);
  o.w = (unsigned)f2bf(b.z) | ((unsigned)f2bf(b.w) << 16);
  ((uint4*)out)[i] = o;
}

// Wt[r][o][k] (bf16, transposed) = sum_b comp[r,b] * V[b,k,o]
__global__ void compute_w(const float* __restrict__ comp, const float* __restrict__ V,
                          unsigned short* __restrict__ Wt, int IO) {
  int idx = blockIdx.x * blockDim.x + threadIdx.x;
  if (idx >= RELS * IO * HDIM) return;
  int k = idx & (HDIM - 1);
  int o = (idx >> 7) % IO;
  int r = idx / (IO * HDIM);
  float s = 0.f;
#pragma unroll
  for (int b = 0; b < RELS; b++)
    s = fmaf(comp[r * RELS + b], V[(size_t)b * HDIM * IO + (size_t)k * IO + o], s);
  Wt[idx] = f2bf(s);
}

__global__ void hist_bins(const int* __restrict__ dst, const int* __restrict__ etype,
                          int n, int nbins, int* __restrict__ counts) {
  __shared__ int lh[MAXBINS];
  for (int j = threadIdx.x; j < nbins; j += blockDim.x) lh[j] = 0;
  __syncthreads();
  for (int i = blockIdx.x * blockDim.x + threadIdx.x; i < n; i += gridDim.x * blockDim.x)
    atomicAdd(&lh[(dst[i] / DSTBLK) * RELS + etype[i]], 1);
  __syncthreads();
  for (int j = threadIdx.x; j < nbins; j += blockDim.x) {
    int c = lh[j];
    if (c) atomicAdd(&counts[j], c);
  }
}

// exclusive scan of counts padded to multiples of 16 (parallel prefix)
__global__ void scan_offsets(const int* __restrict__ counts, int* __restrict__ offsets, int nbins) {
  __shared__ int csum[256];
  const int t = threadIdx.x;
  const int CH = (nbins + 255) / 256;
  int lo = t * CH, hi = min(lo + CH, nbins);
  int s = 0;
  for (int i = lo; i < hi; i++) s += (counts[i] + 15) & ~15;
  csum[t] = s;
  __syncthreads();
#pragma unroll
  for (int d = 1; d < 256; d <<= 1) {  // Hillis-Steele inclusive scan
    int v = (t >= d) ? csum[t - d] : 0;
    __syncthreads();
    csum[t] += v;
    __syncthreads();
  }
  int run = (t == 0) ? 0 : csum[t - 1];
  for (int i = lo; i < hi; i++) {
    offsets[i] = run;
    run += (counts[i] + 15) & ~15;
  }
  if (lo < nbins && hi == nbins) offsets[nbins] = run;
}

// ebuf[p] = {src | dloc<<20, norm_f32_bits}; dloc = d % DSTBLK (7 bits).
// Pad slots unwritten; all consumers guard by real counts.
__global__ void scatter_bins(const int* __restrict__ src, const int* __restrict__ dst,
                             const int* __restrict__ etype, const float* __restrict__ norm,
                             int n, const int* __restrict__ offsets, int* __restrict__ cursor,
                             uint2* __restrict__ ebuf) {
  for (int i = blockIdx.x * blockDim.x + threadIdx.x; i < n; i += gridDim.x * blockDim.x) {
    int d = dst[i];
    int blk = d / DSTBLK;
    int b = blk * RELS + etype[i];
    int p = offsets[b] + atomicAdd(&cursor[b], 1);
    ebuf[p] = make_uint2((unsigned)src[i] | ((unsigned)(d - blk * DSTBLK) << 20),
                         __float_as_uint(norm[i]));
  }
}

// One phase (parity CB literal): (1) entries(ci+3)+hentry(ci+2) -> O-set,
// (2) GEMM1 on xs[CB] -> dacc regs, (3) gathers(ci+2) from I-entries,
// (4) lane-local cvt_pk pack (B-frag) + agg pacc += pmat[CB] @ B,
// (5) write xs[CB^1]/pmat[CB^1] (hslot column) from I-set, (6) barrier.
// All I/O pipeline values are plain named locals -> nothing demotable.
#define PHASE(CB, iE0, iE1, iG0, iG1, iH, oE0, oE1, oG0, oG1, oH, PDW)          \
  {                                                                             \
    int2 dc = descS[ci];                                                        \
    const int nRows = dc.y & 0xFF;                                              \
    const int rel = dc.y >> 8;                                                  \
    if (rel != curRel) {                                                        \
      curRel = rel;                                                             \
      const unsigned short* Wr = Wt + (size_t)rel * OUT * HDIM;                 \
      _Pragma("unroll") for (int ks = 0; ks < 4; ks++)                          \
          _Pragma("unroll") for (int nt = 0; nt < NT; nt++)                     \
              wf[ks][nt] = *(const bf16x8*)(Wr +                                \
                  (size_t)(colBase + nt * 16 + l16) * HDIM + ks * 32 + quad * 8); \
    }                                                                           \
    int2 d3 = (ci + 3 < nCh) ? descS[ci + 3] : make_int2(0, 0);                 \
    const int n3 = d3.y & 0xFF;                                                 \
    if (r0 < n3) oE0 = ebuf[d3.x + r0];                                         \
    if (16 + r0 < n3) oE1 = ebuf[d3.x + 16 + r0];                               \
    if (isHandler && myCol < n2) oH = ebuf[descS[ci + 2].x + myCol];            \
    f32x4 dacc[2][NT] = {};                                                     \
    _Pragma("unroll") for (int mt = 0; mt < 2; mt++) {                          \
      if (mt * 16 < nRows) {                                                    \
        __builtin_amdgcn_s_setprio(1);                                          \
        _Pragma("unroll") for (int ks = 0; ks < 4; ks++) {                      \
          bf16x8 a = *(const bf16x8*)&xs[CB][mt * 16 + l16][ks * 32 + quad * 8]; \
          _Pragma("unroll") for (int nt = 0; nt < NT; nt++)                     \
              dacc[mt][nt] = __builtin_amdgcn_mfma_f32_16x16x32_bf16(           \
                  a, wf[ks][nt], dacc[mt][nt], 0, 0, 0);                        \
        }                                                                       \
        __builtin_amdgcn_s_setprio(0);                                          \
      }                                                                         \
    }                                                                           \
    if (r0 < n2) oG0 = *(const uint4*)(Xb + (size_t)(iE0.x & 0xFFFFFu) * HDIM + k8 * 8); \
    if (16 + r0 < n2) oG1 = *(const uint4*)(Xb + (size_t)(iE1.x & 0xFFFFFu) * HDIM + k8 * 8); \
    {                                                                           \
      bf16x8 bfv[NT];                                                           \
      _Pragma("unroll") for (int nt = 0; nt < NT; nt++) {                       \
        uint4 bw;                                                               \
        bw.x = cvtpk(dacc[0][nt][0], dacc[0][nt][1]);                           \
        bw.y = cvtpk(dacc[0][nt][2], dacc[0][nt][3]);                           \
        bw.z = cvtpk(dacc[1][nt][0], dacc[1][nt][1]);                           \
        bw.w = cvtpk(dacc[1][nt][2], dacc[1][nt][3]);                           \
        bfv[nt] = *(bf16x8*)&bw;                                                \
      }                                                                         \
      __builtin_amdgcn_s_setprio(1);                                            \
      _Pragma("unroll") for (int mt = 0; mt < MT_P; mt++) {                     \
        bf16x8 a = *(const bf16x8*)&pmat[CB][mt * 16 + l16][quad * 8];          \
        _Pragma("unroll") for (int nt = 0; nt < NT; nt++)                       \
            pacc[mt][nt] = __builtin_amdgcn_mfma_f32_16x16x32_bf16(             \
                a, bfv[nt], pacc[mt][nt], 0, 0, 0);                             \
      }                                                                         \
      __builtin_amdgcn_s_setprio(0);                                            \
    }                                                                           \
    if (r0 < n1) *(uint4*)&xs[CB ^ 1][r0][k8 * 8] = iG0;                        \
    if (16 + r0 < n1) *(uint4*)&xs[CB ^ 1][16 + r0][k8 * 8] = iG1;              \
    if (isHandler) {                                                            \
      if (PDW >= 0) pmat[CB ^ 1][PDW][hslot] = 0;                               \
      if (myCol < n1) {                                                         \
        int dl = (int)(iH.x >> 20) & 127;                                       \
        pmat[CB ^ 1][dl][hslot] = f2bf(__uint_as_float(iH.y));                  \
        PDW = dl;                                                               \
      } else {                                                                  \
        PDW = -1;                                                               \
      }                                                                         \
    }                                                                           \
    if (ci + 1 < nCh) barrier_nodrain();                                        \
    n1 = n2; n2 = n3; ci++;                                                     \
  }

// One block owns DSTBLK nodes; walks a precomputed chunk-descriptor list.
// Wave w owns out columns [w*OUT/4, +OUT/4).
template <int OUT, bool BF16_RELU_OUT>
__launch_bounds__(256, (OUT == 64) ? 4 : 3)
__global__ void rgcn_layer(const unsigned short* __restrict__ Xb,  // [N][128] bf16
                           const unsigned short* __restrict__ Wt,  // [R][OUT][128] bf16
                           const uint2* __restrict__ ebuf,
                           const int* __restrict__ offsets, const int* __restrict__ counts,
                           const float* __restrict__ bias, void* __restrict__ Hout,
                           int nNodes) {
  constexpr int NT = OUT / 64;  // 2 (OUT=128) or 1 (OUT=64)
  __shared__ __align__(16) unsigned short xs[2][CHUNK][136];  // gathered src rows
  __shared__ __align__(16) unsigned short pmat[2][80][40];    // P[dloc][slot] = bf16(norm)
  __shared__ __align__(8) int2 descS[MAXCH];                  // {base, nRows|rel<<8}
  __shared__ int sBase[16], sCnt[16], sStart[17];

  const int t = threadIdx.x;
  const int w = t >> 6;
  const int lane = t & 63;
  const int quad = lane >> 4;
  const int l16 = lane & 15;
  const int r0 = t >> 4;     // gather row (this thread covers rows r0, r0+16)
  const int k8 = t & 15;     // gather 8-elem column piece
  const bool isHandler = (t & 7) == 0;
  const int myCol = t >> 3;  // handler-owned edge index (0..31, fixed)
  // pmat column slot for edge myCol: eps^-1(e) = q*8 + m*4 + r
  const int hslot = ((myCol >> 2) & 3) * 8 + ((myCol >> 4) & 1) * 4 + (myCol & 3);
  const int nodeBase = blockIdx.x * DSTBLK;
  const int binBase = blockIdx.x * RELS;
  const int colBase = w * (OUT / 4);

  // one-time zero (stale LDS may hold NaN bit patterns; 0 * NaN = NaN)
  for (int i = t; i < 2 * CHUNK * 136 / 8; i += 256) ((uint4*)xs)[i] = make_uint4(0, 0, 0, 0);
  for (int i = t; i < 2 * 80 * 40 / 8; i += 256) ((uint4*)pmat)[i] = make_uint4(0, 0, 0, 0);

  // build chunk descriptor list (bins in relation order -> few W reloads)
  if (t < 16) {
    sBase[t] = offsets[binBase + t];
    sCnt[t] = counts[binBase + t];
  }
  __syncthreads();  // covers zero-init + sBase/sCnt (nothing in flight yet)
  if (t == 0) {
    int run = 0;
#pragma unroll
    for (int b = 0; b < 16; b++) {
      sStart[b] = run;
      run += (sCnt[b] + CHUNK - 1) / CHUNK;
    }
    sStart[16] = min(run, MAXCH);
  }
  __syncthreads();
  if (t < 16) {
    int st = sStart[t], ba = sBase[t], c = sCnt[t];
    for (int j = 0; j * CHUNK < c; j++)
      if (st + j < MAXCH)
        descS[st + j] = make_int2(ba + j * CHUNK, min(CHUNK, c - j * CHUNK) | (t << 8));
  }
  __syncthreads();
  const int nCh = sStart[16];

  f32x4 pacc[MT_P][NT] = {};  // persistent dst accumulator

  // ping/pong pipeline values as PLAIN NAMED LOCALS (nothing demotable):
  // q-set consumed by even phases, p-set by odd phases.
  uint2 qE0, qE1, pE0, pE1;  // ebuf entries for the chunk gathered next phase
  uint4 qG0, qG1, pG0, pG1;  // gathered xs rows, written to LDS next phase
  uint2 qH, pH;              // handler ebuf entry, written to pmat next phase
  int pd0 = -1, pd1 = -1;    // handler prev-entry tracker per pmat buffer
  int n1 = 0, n2 = 0;        // rows(ci+1), rows(ci+2)

  // prologue (acts as phase -1): stage chunk 0; prime q = {entries(2),
  // gathers(1), hentry(1)}; full latency exposed once per block.
  if (nCh > 0) {
    int2 d0 = descS[0];
    int2 d1 = (nCh > 1) ? descS[1] : make_int2(0, 0);
    int2 d2 = (nCh > 2) ? descS[2] : make_int2(0, 0);
    const int rows0 = d0.y & 0xFF;
    n1 = d1.y & 0xFF;
    n2 = d2.y & 0xFF;
    uint2 a0, a1, am, e10, e11;
    if (r0 < rows0) a0 = ebuf[d0.x + r0];
    if (16 + r0 < rows0) a1 = ebuf[d0.x + 16 + r0];
    if (isHandler && myCol < rows0) am = ebuf[d0.x + myCol];
    if (r0 < n1) e10 = ebuf[d1.x + r0];
    if (16 + r0 < n1) e11 = ebuf[d1.x + 16 + r0];
    if (isHandler && myCol < n1) qH = ebuf[d1.x + myCol];
    if (r0 < n2) qE0 = ebuf[d2.x + r0];
    if (16 + r0 < n2) qE1 = ebuf[d2.x + 16 + r0];
    // stage chunk 0 into xs[0]/pmat[0]
    if (r0 < rows0)
      *(uint4*)&xs[0][r0][k8 * 8] =
          *(const uint4*)(Xb + (size_t)(a0.x & 0xFFFFFu) * HDIM + k8 * 8);
    if (16 + r0 < rows0)
      *(uint4*)&xs[0][16 + r0][k8 * 8] =
          *(const uint4*)(Xb + (size_t)(a1.x & 0xFFFFFu) * HDIM + k8 * 8);
    if (isHandler && myCol < rows0) {
      int dl = (int)(am.x >> 20) & 127;
      pmat[0][dl][hslot] = f2bf(__uint_as_float(am.y));
      pd0 = dl;
    }
    // issue gathers for chunk 1 (e1* landed or nearly so by now)
    if (r0 < n1) qG0 = *(const uint4*)(Xb + (size_t)(e10.x & 0xFFFFFu) * HDIM + k8 * 8);
    if (16 + r0 < n1) qG1 = *(const uint4*)(Xb + (size_t)(e11.x & 0xFFFFFu) * HDIM + k8 * 8);
  }
  barrier_nodrain();  // q prefetches stay in flight

  int curRel = -1;
  bf16x8 wf[4][NT];

  // 2x-unrolled driver: even phases read q write p; odd phases reverse.
  int ci = 0;
  while (ci < nCh) {
    PHASE(0, qE0, qE1, qG0, qG1, qH, pE0, pE1, pG0, pG1, pH, pd1)
    if (ci >= nCh) break;
    PHASE(1, pE0, pE1, pG0, pG1, pH, qE0, qE1, qG0, qG1, qH, pd0)
  }

  // epilogue: each (node, col) owned by exactly one lane -> plain stores
#pragma unroll
  for (int mt = 0; mt < MT_P; mt++) {
#pragma unroll
    for (int reg = 0; reg < 4; reg++) {
      int ld = mt * 16 + quad * 4 + reg;
      int node = nodeBase + ld;
      if (ld < DSTBLK && node < nNodes) {
#pragma unroll
        for (int nt = 0; nt < NT; nt++) {
          int col = colBase + nt * 16 + l16;
          float v = pacc[mt][nt][reg] + bias[col];
          if constexpr (BF16_RELU_OUT)
            ((unsigned short*)Hout)[(size_t)node * OUT + col] = f2bf(fmaxf(v, 0.f));
          else
            ((float*)Hout)[(size_t)node * OUT + col] = v;
        }
      }
    }
  }
}

extern "C" void kernel_launch(void* const* d_in, const int* in_sizes, int n_in,
                              void* d_out, int out_size, void* d_ws, size_t ws_size,
                              hipStream_t stream) {
  const int*   src   = (const int*)d_in[1];
  const int*   dst   = (const int*)d_in[2];
  const int*   etype = (const int*)d_in[3];
  const float* norm  = (const float*)d_in[4];
  const float* emb   = (const float*)d_in[5];
  const float* V1    = (const float*)d_in[6];
  const float* comp1 = (const float*)d_in[7];
  const float* bias1 = (const float*)d_in[8];
  const float* V2    = (const float*)d_in[9];
  const float* comp2 = (const float*)d_in[10];
  const float* bias2 = (const float*)d_in[11];
  float* out = (float*)d_out;

  const int N = in_sizes[0];  // 50000
  const int E = in_sizes[1];  // 1000000
  const int H = 128, O = 64;
  const int NB = (N + DSTBLK - 1) / DSTBLK;  // 758
  const int NBINS = NB * RELS;               // 12128
  const int EPAD_MAX = E + NBINS * 16;

  char* ws = (char*)d_ws;
  size_t off = 0;
  auto alloc = [&](size_t bytes) -> void* {
    void* p = ws + off;
    off += (bytes + 255) & ~(size_t)255;
    return p;
  };
  unsigned short* W1t  = (unsigned short*)alloc(sizeof(short) * RELS * H * H);
  unsigned short* W2t  = (unsigned short*)alloc(sizeof(short) * RELS * O * H);
  unsigned short* embh = (unsigned short*)alloc(sizeof(short) * (size_t)N * H);
  unsigned short* h1b  = (unsigned short*)alloc(sizeof(short) * (size_t)N * H);
  uint2* ebuf = (uint2*)alloc(sizeof(uint2) * EPAD_MAX);
  int* counts  = (int*)alloc(sizeof(int) * NBINS);
  int* cursor  = (int*)alloc(sizeof(int) * NBINS);
  int* offsets = (int*)alloc(sizeof(int) * (NBINS + 1));

  hipMemsetAsync(counts, 0, sizeof(int) * NBINS, stream);
  hipMemsetAsync(cursor, 0, sizeof(int) * NBINS, stream);

  cvt_bf16<<<((size_t)N * H / 8 + 255) / 256, 256, 0, stream>>>(emb, embh, N * H / 8);
  compute_w<<<(RELS * H * H + 255) / 256, 256, 0, stream>>>(comp1, V1, W1t, H);
  compute_w<<<(RELS * O * H + 255) / 256, 256, 0, stream>>>(comp2, V2, W2t, O);
  hist_bins<<<256, 256, 0, stream>>>(dst, etype, E, NBINS, counts);
  scan_offsets<<<1, 256, 0, stream>>>(counts, offsets, NBINS);
  scatter_bins<<<1024, 256, 0, stream>>>(src, dst, etype, norm, E, offsets, cursor, ebuf);

  rgcn_layer<128, true><<<NB, 256, 0, stream>>>(embh, W1t, ebuf, offsets, counts, bias1, (void*)h1b, N);
  rgcn_layer<64, false><<<NB, 256, 0, stream>>>(h1b, W2t, ebuf, offsets, counts, bias2, (void*)out, N);
}